// Round 14
// baseline (98.843 us; speedup 1.0000x reference)
//
#include <hip/hip_runtime.h>

// SVF: linear time-varying 2-state recurrence as an associative scan over
// affine maps (A,b): s_t = A_t s_{t-1} + b_t.
//
// TWO-DEEP PIPELINED WAVE-AUTONOMOUS structure. R13's ledger insight:
// R8 moved 64 MB in ~44 us, R13 moved 88 MB in ~42 us -- time is
// invariant in BYTES, so the kernels are latency/lifetime-bound, not
// BW-bound. The 6.2 TB/s harness fill and the 6.29 TB/s m13 copy differ
// from ALL 13 of our variants in exactly one way: their threads LOOP,
// keeping loads continuously in flight; ours were one-shot (one load
// burst -> drain -> die), paying a full exposed latency window per
// thread lifetime. Fix: each wave owns TWO independent chunks with all
// loads issued up front -- chunk B's 12 loads fly while chunk A drains
// and computes, doubling sustained MLP per wave.
//
// Geometry: chunk = one wave-visit of 512 steps (8/lane); 4096 chunks;
// 2048 waves (512 blocks x 256 thr) x 2 chunks each. Zero __syncthreads,
// zero atomics (kernel boundary carries the cross-chunk dependency,
// proven safe all session). Priors resolved by R13's parallel
// identity-padded lane scan (proven correct).

#define BATCH  64
#define SEQ    32768
#define CLEN   512                  // steps per chunk
#define CPR    (SEQ / CLEN)         // 64 chunks per row
#define NCHUNK (BATCH * CPR)        // 4096
#define TPB    256
#define WPB    (TPB / 64)           // 4 waves per block
#define KPW    2                    // chunks per wave (pipeline depth)
#define TOTW   (NCHUNK / KPW)       // 2048 waves per dispatch
#define NBLK   (TOTW / WPB)         // 512 blocks
#define LSTEPS (CLEN / 64)          // 8 steps per lane

struct Aff { float a00, a01, a10, a11, b0, b1; };

// Apply 'e' (earlier) first, then 'l' (later).
__device__ __forceinline__ Aff compose(const Aff l, const Aff e) {
    Aff r;
    r.a00 = fmaf(l.a00, e.a00, l.a01 * e.a10);
    r.a01 = fmaf(l.a00, e.a01, l.a01 * e.a11);
    r.a10 = fmaf(l.a10, e.a00, l.a11 * e.a10);
    r.a11 = fmaf(l.a10, e.a01, l.a11 * e.a11);
    r.b0  = fmaf(l.a00, e.b0, fmaf(l.a01, e.b1, l.b0));
    r.b1  = fmaf(l.a10, e.b0, fmaf(l.a11, e.b1, l.b1));
    return r;
}

__device__ __forceinline__ Aff step_affine(float gi, float Ri, float xi) {
    float T  = 1.0f / fmaf(gi, gi + Ri, 1.0f);   // 1/(1+g*(g+2R))
    float Tg = T * gi;
    Aff r;
    r.a00 = 2.0f * T - 1.0f;
    r.a01 = -2.0f * Tg;
    r.a10 = 2.0f * Tg;
    r.a11 = 2.0f * fmaf(Tg, Ri, T) - 1.0f;       // 2*T*(2R*g+1)-1
    r.b0  = 2.0f * Tg * xi;
    r.b1  = gi * r.b0;
    return r;
}

__device__ __forceinline__ Aff shfl_up_aff(const Aff v, int d) {
    Aff r;
    r.a00 = __shfl_up(v.a00, d, 64);
    r.a01 = __shfl_up(v.a01, d, 64);
    r.a10 = __shfl_up(v.a10, d, 64);
    r.a11 = __shfl_up(v.a11, d, 64);
    r.b0  = __shfl_up(v.b0,  d, 64);
    r.b1  = __shfl_up(v.b1,  d, 64);
    return r;
}

__device__ __forceinline__ Aff shfl_down_aff(const Aff v, int d) {
    Aff r;
    r.a00 = __shfl_down(v.a00, d, 64);
    r.a01 = __shfl_down(v.a01, d, 64);
    r.a10 = __shfl_down(v.a10, d, 64);
    r.a11 = __shfl_down(v.a11, d, 64);
    r.b0  = __shfl_down(v.b0,  d, 64);
    r.b1  = __shfl_down(v.b1,  d, 64);
    return r;
}

__device__ __forceinline__ void apply_aff(const Aff a, float& s0, float& s1) {
    float n0 = fmaf(a.a00, s0, fmaf(a.a01, s1, a.b0));
    float n1 = fmaf(a.a10, s0, fmaf(a.a11, s1, a.b1));
    s0 = n0; s1 = n1;
}

__device__ __forceinline__ void load8(const float* __restrict__ p, int base, float v[8]) {
    float4 a = *reinterpret_cast<const float4*>(p + base);
    float4 b = *reinterpret_cast<const float4*>(p + base + 4);
    v[0]=a.x; v[1]=a.y; v[2]=a.z; v[3]=a.w; v[4]=b.x; v[5]=b.y; v[6]=b.z; v[7]=b.w;
}

__device__ __forceinline__ Aff load_prior(const float4* __restrict__ cp,
                                          int cid, int lane) {
    const int row = cid >> 6;                // CPR == 64
    const int c   = cid & (CPR - 1);
    Aff pr;
    if (lane < c) {
        const float4* p = cp + 2 * ((row << 6) + lane);
        float4 A = p[0], Bv = p[1];
        pr.a00 = A.x; pr.a01 = A.y; pr.a10 = A.z; pr.a11 = A.w;
        pr.b0  = Bv.x; pr.b1 = Bv.y;
    } else {
        pr.a00 = 1.0f; pr.a01 = 0.0f; pr.a10 = 0.0f; pr.a11 = 1.0f;
        pr.b0  = 0.0f; pr.b1 = 0.0f;
    }
    return pr;
}

// Ordered wave tree-reduce + store chunk total (lane 0).
__device__ __forceinline__ void reduce_store(
    int lane, int cid,
    const float (&gv)[LSTEPS], const float (&rv)[LSTEPS],
    const float (&xv)[LSTEPS], float4* __restrict__ chunk_comp)
{
    Aff acc = step_affine(gv[0], rv[0], xv[0]);
#pragma unroll
    for (int i = 1; i < LSTEPS; ++i)
        acc = compose(step_affine(gv[i], rv[i], xv[i]), acc);
#pragma unroll
    for (int off = 1; off < 64; off <<= 1) {
        Aff hi = shfl_down_aff(acc, off);   // hi covers the LATER span
        acc = compose(hi, acc);
    }
    if (lane == 0) {
        chunk_comp[2 * cid]     = make_float4(acc.a00, acc.a01, acc.a10, acc.a11);
        chunk_comp[2 * cid + 1] = make_float4(acc.b0,  acc.b1,  0.0f,    0.0f);
    }
}

// Own-chunk scan + prior lane-scan + emit + store (proven R13 body).
__device__ __forceinline__ void scan_emit(
    int lane, int base, Aff pr,
    const float (&gv)[LSTEPS], const float (&rv)[LSTEPS],
    const float (&xv)[LSTEPS], const float (&mv)[24],
    float* __restrict__ out)
{
    Aff acc = step_affine(gv[0], rv[0], xv[0]);
#pragma unroll
    for (int i = 1; i < LSTEPS; ++i)
        acc = compose(step_affine(gv[i], rv[i], xv[i]), acc);

#pragma unroll
    for (int off = 1; off < 64; off <<= 1) {
        Aff p = shfl_up_aff(acc, off);
        if (lane >= off) acc = compose(acc, p);
    }
    Aff excl = shfl_up_aff(acc, 1);          // lane-1's inclusive = my exclusive

    // Parallel prior scan (identity-padded); lane 63 = T_{c-1} o..o T_0.
#pragma unroll
    for (int off = 1; off < 64; off <<= 1) {
        Aff p = shfl_up_aff(pr, off);
        if (lane >= off) pr = compose(pr, p);
    }
    Aff ptot;
    ptot.a00 = __shfl(pr.a00, 63, 64); ptot.a01 = __shfl(pr.a01, 63, 64);
    ptot.a10 = __shfl(pr.a10, 63, 64); ptot.a11 = __shfl(pr.a11, 63, 64);
    ptot.b0  = __shfl(pr.b0,  63, 64); ptot.b1  = __shfl(pr.b1,  63, 64);

    float s0 = 1.0f, s1 = 1.0f;
    apply_aff(ptot, s0, s1);
    if (lane > 0) apply_aff(excl, s0, s1);

    float ov[LSTEPS];
#pragma unroll
    for (int i = 0; i < LSTEPS; ++i) {
        float gi = gv[i], Ri = rv[i], xi = xv[i];
        float T  = 1.0f / fmaf(gi, gi + Ri, 1.0f);
        float w  = fmaf(gi, xi, s0);                         // g*x + s0
        float Y0 = T * fmaf(-gi, s1, w);                     // bp
        float Y1 = T * fmaf(gi, w, fmaf(Ri, gi, 1.0f) * s1); // lp
        float hp = xi - Ri * Y0 - Y1;
        ov[i] = fmaf(Ri * mv[3*i], Y0, fmaf(mv[3*i+1], Y1, mv[3*i+2] * hp));
        s0 = fmaf(2.0f, Y0, -s0);
        s1 = fmaf(2.0f, Y1, -s1);
    }

    *reinterpret_cast<float4*>(out + base)     = make_float4(ov[0], ov[1], ov[2], ov[3]);
    *reinterpret_cast<float4*>(out + base + 4) = make_float4(ov[4], ov[5], ov[6], ov[7]);
}

// -------- kernel 1: chunk totals, 2 chunks/wave, loads interleaved --------
__global__ __launch_bounds__(TPB) void svf_tot(
    const float* __restrict__ audio, const float* __restrict__ g,
    const float* __restrict__ twoR, float4* __restrict__ chunk_comp)
{
    const int t    = threadIdx.x;
    const int lane = t & 63;
    const int wv   = t >> 6;
    const int gw   = blockIdx.x * WPB + wv;
    const int cidA = gw, cidB = gw + TOTW;
    const int baseA = cidA * CLEN + lane * LSTEPS;
    const int baseB = cidB * CLEN + lane * LSTEPS;

    // ALL 12 loads issued before any compute: B flies while A drains.
    float gvA[LSTEPS], rvA[LSTEPS], xvA[LSTEPS];
    float gvB[LSTEPS], rvB[LSTEPS], xvB[LSTEPS];
    load8(g, baseA, gvA); load8(twoR, baseA, rvA); load8(audio, baseA, xvA);
    load8(g, baseB, gvB); load8(twoR, baseB, rvB); load8(audio, baseB, xvB);

    reduce_store(lane, cidA, gvA, rvA, xvA, chunk_comp);
    reduce_store(lane, cidB, gvB, rvB, xvB, chunk_comp);
}

// -------- kernel 2: scan + emit, 2 chunks/wave, loads interleaved --------
__global__ __launch_bounds__(TPB) void svf_emit(
    const float* __restrict__ audio, const float* __restrict__ g,
    const float* __restrict__ twoR, const float* __restrict__ mix,
    const float4* __restrict__ chunk_comp, float* __restrict__ out)
{
    const int t    = threadIdx.x;
    const int lane = t & 63;
    const int wv   = t >> 6;
    const int gw   = blockIdx.x * WPB + wv;
    const int cidA = gw, cidB = gw + TOTW;
    const int baseA = cidA * CLEN + lane * LSTEPS;
    const int baseB = cidB * CLEN + lane * LSTEPS;

    // ALL loads (priors + 2x{g,R,x,mix}) issued before any compute.
    Aff prA = load_prior(chunk_comp, cidA, lane);
    Aff prB = load_prior(chunk_comp, cidB, lane);

    float gvA[LSTEPS], rvA[LSTEPS], xvA[LSTEPS];
    float gvB[LSTEPS], rvB[LSTEPS], xvB[LSTEPS];
    load8(g, baseA, gvA); load8(twoR, baseA, rvA); load8(audio, baseA, xvA);
    load8(g, baseB, gvB); load8(twoR, baseB, rvB); load8(audio, baseB, xvB);

    float mvA[24], mvB[24];
    const float4* m4A = reinterpret_cast<const float4*>(mix + 3 * baseA);
    const float4* m4B = reinterpret_cast<const float4*>(mix + 3 * baseB);
#pragma unroll
    for (int k = 0; k < 6; ++k) {
        float4 m = m4A[k];
        mvA[4*k+0]=m.x; mvA[4*k+1]=m.y; mvA[4*k+2]=m.z; mvA[4*k+3]=m.w;
    }
#pragma unroll
    for (int k = 0; k < 6; ++k) {
        float4 m = m4B[k];
        mvB[4*k+0]=m.x; mvB[4*k+1]=m.y; mvB[4*k+2]=m.z; mvB[4*k+3]=m.w;
    }

    scan_emit(lane, baseA, prA, gvA, rvA, xvA, mvA, out);
    scan_emit(lane, baseB, prB, gvB, rvB, xvB, mvB, out);
}

extern "C" void kernel_launch(void* const* d_in, const int* in_sizes, int n_in,
                              void* d_out, int out_size, void* d_ws, size_t ws_size,
                              hipStream_t stream) {
    const float* audio = (const float*)d_in[0];
    const float* g     = (const float*)d_in[1];
    const float* twoR  = (const float*)d_in[2];
    const float* mix   = (const float*)d_in[3];
    float* out = (float*)d_out;

    // ws: [chunk_comp: 4096 x 32 B = 128 KB]. Kernel boundary provides
    // cross-XCD visibility; k2 reads only what k1 wrote this launch.
    float4* chunk_comp = (float4*)d_ws;

    svf_tot<<<NBLK, TPB, 0, stream>>>(audio, g, twoR, chunk_comp);
    svf_emit<<<NBLK, TPB, 0, stream>>>(audio, g, twoR, mix, chunk_comp, out);
}

// Round 15
// 93.747 us; speedup vs baseline: 1.0544x; 1.0544x over previous
//
#include <hip/hip_runtime.h>

// SVF: linear time-varying 2-state recurrence as an associative scan over
// affine maps (A,b): s_t = A_t s_{t-1} + b_t.
//
// FINAL (session-best, R13 = 93.4 us): zero-barrier, wave-autonomous
// two-kernel structure. Chunk == one wave: 512 steps (8/lane), 64
// chunks/row, 4096 chunks, 512 blocks x 512 thr. No __syncthreads, no
// atomics; the kernel boundary carries the cross-chunk dependency.
// Priors resolved by a parallel identity-padded lane scan.
//
// 14-round ledger: duplicated-work (R5), dispatch count (R8), sync
// mechanism (R1/2/7/8), occupancy (R9/R10), lockstep barriers (R13),
// and per-thread MLP depth (R14) all tested; time is invariant at
// ~40-42 us of kernel + ~51-55 us unconditional harness overhead
// (256 MiB ws-poison fill ~43 us + resets + launch plumbing). The
// kernels are latency/lifetime-bound (R8: 64 MB in 44 us vs R13: 88 MB
// in 42 us -- byte-count-invariant), and every structural lever moves
// the total by <=2 us. This config is the measured floor.

#define BATCH  64
#define SEQ    32768
#define CLEN   512                  // steps per chunk (one wave)
#define CPR    (SEQ / CLEN)         // 64 chunks per row
#define NCHUNK (BATCH * CPR)        // 4096
#define TPB    512
#define WPB    (TPB / 64)           // 8 waves per block
#define NBLK   (NCHUNK / WPB)       // 512 blocks
#define LSTEPS (CLEN / 64)          // 8 steps per lane

struct Aff { float a00, a01, a10, a11, b0, b1; };

// Apply 'e' (earlier) first, then 'l' (later).
__device__ __forceinline__ Aff compose(const Aff l, const Aff e) {
    Aff r;
    r.a00 = fmaf(l.a00, e.a00, l.a01 * e.a10);
    r.a01 = fmaf(l.a00, e.a01, l.a01 * e.a11);
    r.a10 = fmaf(l.a10, e.a00, l.a11 * e.a10);
    r.a11 = fmaf(l.a10, e.a01, l.a11 * e.a11);
    r.b0  = fmaf(l.a00, e.b0, fmaf(l.a01, e.b1, l.b0));
    r.b1  = fmaf(l.a10, e.b0, fmaf(l.a11, e.b1, l.b1));
    return r;
}

__device__ __forceinline__ Aff step_affine(float gi, float Ri, float xi) {
    float T  = 1.0f / fmaf(gi, gi + Ri, 1.0f);   // 1/(1+g*(g+2R))
    float Tg = T * gi;
    Aff r;
    r.a00 = 2.0f * T - 1.0f;
    r.a01 = -2.0f * Tg;
    r.a10 = 2.0f * Tg;
    r.a11 = 2.0f * fmaf(Tg, Ri, T) - 1.0f;       // 2*T*(2R*g+1)-1
    r.b0  = 2.0f * Tg * xi;
    r.b1  = gi * r.b0;
    return r;
}

__device__ __forceinline__ Aff shfl_up_aff(const Aff v, int d) {
    Aff r;
    r.a00 = __shfl_up(v.a00, d, 64);
    r.a01 = __shfl_up(v.a01, d, 64);
    r.a10 = __shfl_up(v.a10, d, 64);
    r.a11 = __shfl_up(v.a11, d, 64);
    r.b0  = __shfl_up(v.b0,  d, 64);
    r.b1  = __shfl_up(v.b1,  d, 64);
    return r;
}

__device__ __forceinline__ Aff shfl_down_aff(const Aff v, int d) {
    Aff r;
    r.a00 = __shfl_down(v.a00, d, 64);
    r.a01 = __shfl_down(v.a01, d, 64);
    r.a10 = __shfl_down(v.a10, d, 64);
    r.a11 = __shfl_down(v.a11, d, 64);
    r.b0  = __shfl_down(v.b0,  d, 64);
    r.b1  = __shfl_down(v.b1,  d, 64);
    return r;
}

__device__ __forceinline__ void apply_aff(const Aff a, float& s0, float& s1) {
    float n0 = fmaf(a.a00, s0, fmaf(a.a01, s1, a.b0));
    float n1 = fmaf(a.a10, s0, fmaf(a.a11, s1, a.b1));
    s0 = n0; s1 = n1;
}

__device__ __forceinline__ void load8(const float* __restrict__ p, int base, float v[8]) {
    float4 a = *reinterpret_cast<const float4*>(p + base);
    float4 b = *reinterpret_cast<const float4*>(p + base + 4);
    v[0]=a.x; v[1]=a.y; v[2]=a.z; v[3]=a.w; v[4]=b.x; v[5]=b.y; v[6]=b.z; v[7]=b.w;
}

// -------- kernel 1: per-chunk totals. No LDS, no barriers. --------
__global__ __launch_bounds__(TPB) void svf_tot(
    const float* __restrict__ audio, const float* __restrict__ g,
    const float* __restrict__ twoR, float4* __restrict__ chunk_comp)
{
    const int t    = threadIdx.x;
    const int lane = t & 63;
    const int wv   = t >> 6;
    const int cid  = blockIdx.x * WPB + wv;
    const int base = cid * CLEN + lane * LSTEPS;

    float gv[LSTEPS], rv[LSTEPS], xv[LSTEPS];
    load8(g, base, gv); load8(twoR, base, rv); load8(audio, base, xv);

    Aff acc = step_affine(gv[0], rv[0], xv[0]);
#pragma unroll
    for (int i = 1; i < LSTEPS; ++i)
        acc = compose(step_affine(gv[i], rv[i], xv[i]), acc);

    // Ordered tree reduce: lane 0 ends with the wave's 64 lane-segments
    // composed in time order (hi covers the LATER span at every level).
#pragma unroll
    for (int off = 1; off < 64; off <<= 1) {
        Aff hi = shfl_down_aff(acc, off);
        acc = compose(hi, acc);
    }
    if (lane == 0) {
        chunk_comp[2 * cid]     = make_float4(acc.a00, acc.a01, acc.a10, acc.a11);
        chunk_comp[2 * cid + 1] = make_float4(acc.b0,  acc.b1,  0.0f,    0.0f);
    }
}

// -------- kernel 2: prior resolve + scan + emit. No LDS, no barriers. ----
__global__ __launch_bounds__(TPB) void svf_emit(
    const float* __restrict__ audio, const float* __restrict__ g,
    const float* __restrict__ twoR, const float* __restrict__ mix,
    const float4* __restrict__ chunk_comp, float* __restrict__ out)
{
    const int t    = threadIdx.x;
    const int lane = t & 63;
    const int wv   = t >> 6;
    const int cid  = blockIdx.x * WPB + wv;
    const int row  = cid >> 6;               // CPR == 64
    const int c    = cid & (CPR - 1);
    const int base = cid * CLEN + lane * LSTEPS;

    // Prior chunk totals first (small, L2-resident), then bulk inputs:
    // everything in flight before any compute.
    Aff pr;
    if (lane < c) {
        const float4* cp = chunk_comp + 2 * ((row << 6) + lane);
        float4 A = cp[0], Bv = cp[1];
        pr.a00 = A.x; pr.a01 = A.y; pr.a10 = A.z; pr.a11 = A.w;
        pr.b0  = Bv.x; pr.b1 = Bv.y;
    } else {
        pr.a00 = 1.0f; pr.a01 = 0.0f; pr.a10 = 0.0f; pr.a11 = 1.0f;
        pr.b0  = 0.0f; pr.b1 = 0.0f;
    }

    float gv[LSTEPS], rv[LSTEPS], xv[LSTEPS];
    load8(g, base, gv); load8(twoR, base, rv); load8(audio, base, xv);

    // mix: [B,N,3] -> 24 consecutive floats/lane, 16B-aligned (3*base%4==0).
    const float4* m4 = reinterpret_cast<const float4*>(mix + 3 * base);
    float mv[24];
#pragma unroll
    for (int k = 0; k < 6; ++k) {
        float4 m = m4[k];
        mv[4*k+0]=m.x; mv[4*k+1]=m.y; mv[4*k+2]=m.z; mv[4*k+3]=m.w;
    }

    // Own-chunk per-lane reduce.
    Aff acc = step_affine(gv[0], rv[0], xv[0]);
#pragma unroll
    for (int i = 1; i < LSTEPS; ++i)
        acc = compose(step_affine(gv[i], rv[i], xv[i]), acc);

    // In-wave inclusive scan of own chunk (time order = lane order).
#pragma unroll
    for (int off = 1; off < 64; off <<= 1) {
        Aff p = shfl_up_aff(acc, off);
        if (lane >= off) acc = compose(acc, p);
    }
    Aff excl = shfl_up_aff(acc, 1);          // lane-1's inclusive = my exclusive

    // Parallel prior scan: lane 63's inclusive (identity-padded) =
    // T_{c-1} o ... o T_0. Works for c == 0 (all identity).
#pragma unroll
    for (int off = 1; off < 64; off <<= 1) {
        Aff p = shfl_up_aff(pr, off);
        if (lane >= off) pr = compose(pr, p);
    }
    Aff ptot;
    ptot.a00 = __shfl(pr.a00, 63, 64); ptot.a01 = __shfl(pr.a01, 63, 64);
    ptot.a10 = __shfl(pr.a10, 63, 64); ptot.a11 = __shfl(pr.a11, 63, 64);
    ptot.b0  = __shfl(pr.b0,  63, 64); ptot.b1  = __shfl(pr.b1,  63, 64);

    // Chunk start state = priors applied to s_init = (1,1).
    float s0 = 1.0f, s1 = 1.0f;
    apply_aff(ptot, s0, s1);
    // Lane start state = wave-exclusive prefix applied to chunk start.
    if (lane > 0) apply_aff(excl, s0, s1);

    // Emit 8 steps.
    float ov[LSTEPS];
#pragma unroll
    for (int i = 0; i < LSTEPS; ++i) {
        float gi = gv[i], Ri = rv[i], xi = xv[i];
        float T  = 1.0f / fmaf(gi, gi + Ri, 1.0f);
        float w  = fmaf(gi, xi, s0);                         // g*x + s0
        float Y0 = T * fmaf(-gi, s1, w);                     // bp
        float Y1 = T * fmaf(gi, w, fmaf(Ri, gi, 1.0f) * s1); // lp
        float hp = xi - Ri * Y0 - Y1;
        ov[i] = fmaf(Ri * mv[3*i], Y0, fmaf(mv[3*i+1], Y1, mv[3*i+2] * hp));
        s0 = fmaf(2.0f, Y0, -s0);
        s1 = fmaf(2.0f, Y1, -s1);
    }

    *reinterpret_cast<float4*>(out + base)     = make_float4(ov[0], ov[1], ov[2], ov[3]);
    *reinterpret_cast<float4*>(out + base + 4) = make_float4(ov[4], ov[5], ov[6], ov[7]);
}

extern "C" void kernel_launch(void* const* d_in, const int* in_sizes, int n_in,
                              void* d_out, int out_size, void* d_ws, size_t ws_size,
                              hipStream_t stream) {
    const float* audio = (const float*)d_in[0];
    const float* g     = (const float*)d_in[1];
    const float* twoR  = (const float*)d_in[2];
    const float* mix   = (const float*)d_in[3];
    float* out = (float*)d_out;

    // ws: [chunk_comp: 4096 x 32 B = 128 KB]. Kernel boundary provides
    // cross-XCD visibility; k2 reads only what k1 wrote this launch.
    float4* chunk_comp = (float4*)d_ws;

    svf_tot<<<NBLK, TPB, 0, stream>>>(audio, g, twoR, chunk_comp);
    svf_emit<<<NBLK, TPB, 0, stream>>>(audio, g, twoR, mix, chunk_comp, out);
}